// Round 3
// baseline (447.066 us; speedup 1.0000x reference)
//
#include <hip/hip_runtime.h>
#include <hip/hip_bf16.h>

#define N 8192
#define DIN 256
#define DOUT 64
#define JSPLIT 8
#define JSPAN (N / JSPLIT)      // 1024
#define ROWTILE 64
#define NITILES (N / ROWTILE)   // 128
#define LEAKY 0.2f

typedef __attribute__((ext_vector_type(8))) short bf16x8;
typedef __attribute__((ext_vector_type(4))) float f32x4;

// workspace layout (256B-aligned slices)
#define OFF_ZT   ((size_t)0)                              // DOUT*N*2  = 1 MiB
#define OFF_SI   (OFF_ZT + (size_t)DOUT * N * 2)          // N*4
#define OFF_SJ   (OFF_SI + (size_t)N * 4)                 // N*4
#define OFF_C    (OFF_SJ + (size_t)N * 4)                 // 256
#define OFF_PDEN (OFF_C + 256)                            // JSPLIT*N*4
#define OFF_PNUM (OFF_PDEN + (size_t)JSPLIT * N * 4)      // JSPLIT*N*DOUT*4

static __device__ __forceinline__ short f2bf(float f) {
  __hip_bfloat16 h = __float2bfloat16(f);
  union { __hip_bfloat16 h; short s; } u;
  u.h = h;
  return u.s;
}

// ---------------- kernel 1: z = x@W ; si = z@a1 ; sj = z@a2 ; zT(bf16) -------
__global__ __launch_bounds__(256) void gat_proj(
    const float* __restrict__ x, const float* __restrict__ W,
    const float* __restrict__ a, __hip_bfloat16* __restrict__ zT,
    float* __restrict__ si, float* __restrict__ sj) {
  const int lane = threadIdx.x & 63;
  const int wave = threadIdx.x >> 6;
  const int rowbase = blockIdx.x * 16 + wave * 4;  // 4 rows per wave, lane = out col
  float acc[4] = {0.f, 0.f, 0.f, 0.f};
  for (int k = 0; k < DIN; k += 4) {
    const float w0 = W[(k + 0) * DOUT + lane];
    const float w1 = W[(k + 1) * DOUT + lane];
    const float w2 = W[(k + 2) * DOUT + lane];
    const float w3 = W[(k + 3) * DOUT + lane];
#pragma unroll
    for (int r = 0; r < 4; ++r) {
      const float4 xv = *reinterpret_cast<const float4*>(&x[(size_t)(rowbase + r) * DIN + k]);
      acc[r] += xv.x * w0 + xv.y * w1 + xv.z * w2 + xv.w * w3;
    }
  }
  const float a1l = a[lane];
  const float a2l = a[DOUT + lane];
#pragma unroll
  for (int r = 0; r < 4; ++r) {
    const int row = rowbase + r;
    zT[(size_t)lane * N + row] = __float2bfloat16(acc[r]);
    float v1 = acc[r] * a1l;
    float v2 = acc[r] * a2l;
#pragma unroll
    for (int m = 1; m < 64; m <<= 1) {
      v1 += __shfl_xor(v1, m);
      v2 += __shfl_xor(v2, m);
    }
    if (lane == 0) { si[row] = v1; sj[row] = v2; }
  }
}

// ---------------- kernel 2: C = leaky_relu(max(si) + max(sj)) ----------------
__global__ __launch_bounds__(1024) void gat_maxc(
    const float* __restrict__ si, const float* __restrict__ sj,
    float* __restrict__ Cout) {
  __shared__ float sm[32];
  const int tid = threadIdx.x;
  float m1 = -1e30f, m2 = -1e30f;
  for (int i = tid; i < N; i += 1024) {
    m1 = fmaxf(m1, si[i]);
    m2 = fmaxf(m2, sj[i]);
  }
#pragma unroll
  for (int m = 1; m < 64; m <<= 1) {
    m1 = fmaxf(m1, __shfl_xor(m1, m));
    m2 = fmaxf(m2, __shfl_xor(m2, m));
  }
  const int wave = tid >> 6, lane = tid & 63;
  if (lane == 0) { sm[wave] = m1; sm[16 + wave] = m2; }
  __syncthreads();
  if (tid == 0) {
    float M1 = sm[0], M2 = sm[16];
    for (int w = 1; w < 16; ++w) {
      M1 = fmaxf(M1, sm[w]);
      M2 = fmaxf(M2, sm[16 + w]);
    }
    const float t = M1 + M2;
    *Cout = t > 0.f ? t : LEAKY * t;
  }
}

// ---------------- kernel 3: fused mask+exp + partial P@z (MFMA) --------------
// grid = NITILES * JSPLIT blocks of 256 (4 waves x 16 rows). Each block scans
// JSPAN j's in K=32 steps; P built directly in the 16x16x32 A-fragment layout.
__global__ __launch_bounds__(256, 4) void gat_main(
    const int* __restrict__ adj, const float* __restrict__ si,
    const float* __restrict__ sj, const __hip_bfloat16* __restrict__ zT,
    const float* __restrict__ Cptr, float* __restrict__ pnum,
    float* __restrict__ pden) {
  const int lane = threadIdx.x & 63;
  const int wave = threadIdx.x >> 6;
  const int itile = blockIdx.x % NITILES;
  const int jchunk = blockIdx.x / NITILES;
  const int r16 = lane & 15;
  const int kgrp = lane >> 4;
  const int row = itile * ROWTILE + wave * 16 + r16;

  const float C = *Cptr;
  const float sir = si[row];
  const int* __restrict__ adjrow = adj + (size_t)row * N;

  f32x4 acc[4];
  const f32x4 z4 = {0.f, 0.f, 0.f, 0.f};
#pragma unroll
  for (int dt = 0; dt < 4; ++dt) acc[dt] = z4;
  float dacc = 0.f;

  const int j0base = jchunk * JSPAN;
  for (int j0 = j0base; j0 < j0base + JSPAN; j0 += 32) {
    const int jb = j0 + kgrp * 8;
    const int4 av0 = *reinterpret_cast<const int4*>(adjrow + jb);
    const int4 av1 = *reinterpret_cast<const int4*>(adjrow + jb + 4);
    const float4 sv0 = *reinterpret_cast<const float4*>(sj + jb);
    const float4 sv1 = *reinterpret_cast<const float4*>(sj + jb + 4);

    float p0, p1, p2, p3, p4, p5, p6, p7, t;
    t = sir + sv0.x; t = (t > 0.f ? t : LEAKY * t) - C; p0 = (av0.x > 0) ? __expf(t) : 0.f;
    t = sir + sv0.y; t = (t > 0.f ? t : LEAKY * t) - C; p1 = (av0.y > 0) ? __expf(t) : 0.f;
    t = sir + sv0.z; t = (t > 0.f ? t : LEAKY * t) - C; p2 = (av0.z > 0) ? __expf(t) : 0.f;
    t = sir + sv0.w; t = (t > 0.f ? t : LEAKY * t) - C; p3 = (av0.w > 0) ? __expf(t) : 0.f;
    t = sir + sv1.x; t = (t > 0.f ? t : LEAKY * t) - C; p4 = (av1.x > 0) ? __expf(t) : 0.f;
    t = sir + sv1.y; t = (t > 0.f ? t : LEAKY * t) - C; p5 = (av1.y > 0) ? __expf(t) : 0.f;
    t = sir + sv1.z; t = (t > 0.f ? t : LEAKY * t) - C; p6 = (av1.z > 0) ? __expf(t) : 0.f;
    t = sir + sv1.w; t = (t > 0.f ? t : LEAKY * t) - C; p7 = (av1.w > 0) ? __expf(t) : 0.f;

    dacc += ((p0 + p1) + (p2 + p3)) + ((p4 + p5) + (p6 + p7));

    bf16x8 afr;
    afr[0] = f2bf(p0); afr[1] = f2bf(p1); afr[2] = f2bf(p2); afr[3] = f2bf(p3);
    afr[4] = f2bf(p4); afr[5] = f2bf(p5); afr[6] = f2bf(p6); afr[7] = f2bf(p7);

#pragma unroll
    for (int dt = 0; dt < 4; ++dt) {
      const bf16x8 bfr =
          *reinterpret_cast<const bf16x8*>(zT + (size_t)(dt * 16 + r16) * N + jb);
      acc[dt] = __builtin_amdgcn_mfma_f32_16x16x32_bf16(afr, bfr, acc[dt], 0, 0, 0);
    }
  }

  // denominator: combine the 4 k-groups holding the same row
  dacc += __shfl_xor(dacc, 16);
  dacc += __shfl_xor(dacc, 32);
  if (lane < 16) pden[(size_t)jchunk * N + row] = dacc;

  // C/D layout (16x16x32): col = lane&15, row = (lane>>4)*4 + reg
  float* np = pnum + ((size_t)jchunk * N + (size_t)itile * ROWTILE + wave * 16) * DOUT;
#pragma unroll
  for (int dt = 0; dt < 4; ++dt) {
#pragma unroll
    for (int r = 0; r < 4; ++r) {
      np[(kgrp * 4 + r) * DOUT + dt * 16 + r16] = acc[dt][r];
    }
  }
}

// ---------------- kernel 4: combine partials, divide, bias, relu -------------
__global__ __launch_bounds__(256) void gat_combine(
    const float* __restrict__ pnum, const float* __restrict__ pden,
    const float* __restrict__ b, float* __restrict__ out) {
  const int idx = blockIdx.x * 256 + threadIdx.x;
  const int row = idx >> 6;
  const int d = idx & 63;
  float num = 0.f, den = 0.f;
#pragma unroll
  for (int s = 0; s < JSPLIT; ++s) num += pnum[(size_t)s * N * DOUT + idx];
#pragma unroll
  for (int s = 0; s < JSPLIT; ++s) den += pden[(size_t)s * N + row];
  const float o = num / den + b[d];
  out[idx] = o > 0.f ? o : 0.f;
}

extern "C" void kernel_launch(void* const* d_in, const int* in_sizes, int n_in,
                              void* d_out, int out_size, void* d_ws, size_t ws_size,
                              hipStream_t stream) {
  const float* x = (const float*)d_in[0];
  const int* adj = (const int*)d_in[1];
  const float* W = (const float*)d_in[2];
  const float* a = (const float*)d_in[3];
  const float* b = (const float*)d_in[4];
  float* out = (float*)d_out;
  char* ws = (char*)d_ws;

  __hip_bfloat16* zT = (__hip_bfloat16*)(ws + OFF_ZT);
  float* si = (float*)(ws + OFF_SI);
  float* sj = (float*)(ws + OFF_SJ);
  float* Cb = (float*)(ws + OFF_C);
  float* pden = (float*)(ws + OFF_PDEN);
  float* pnum = (float*)(ws + OFF_PNUM);

  gat_proj<<<dim3(N / 16), dim3(256), 0, stream>>>(x, W, a, zT, si, sj);
  gat_maxc<<<dim3(1), dim3(1024), 0, stream>>>(si, sj, Cb);
  gat_main<<<dim3(NITILES * JSPLIT), dim3(256), 0, stream>>>(adj, si, sj, zT, Cb,
                                                             pnum, pden);
  gat_combine<<<dim3((N * DOUT) / 256), dim3(256), 0, stream>>>(pnum, pden, b, out);
}